// Round 1
// baseline (4805.125 us; speedup 1.0000x reference)
//
#include <hip/hip_runtime.h>
#include <math.h>

// Problem constants
#define S_GRID 32768
#define N_Q    32768
#define N_E    262144
// feature dims: IN=EMB=192, concat=384, 2*HID=384, BOT=192, PREDH=192, OUT=4

__device__ __forceinline__ float gelu_f(float x) {
    return 0.5f * x * (1.0f + erff(x * 0.7071067811865475f));
}

__device__ __forceinline__ float4 f4_fma(float a, float4 w, float4 c) {
    c.x = fmaf(a, w.x, c.x); c.y = fmaf(a, w.y, c.y);
    c.z = fmaf(a, w.z, c.z); c.w = fmaf(a, w.w, c.w);
    return c;
}

// ---------------- sincos embedding of query positions ----------------
// qe[q, d*64 + j] = j<32 ? sin(pos[q,d]*omega[j]) : cos(pos[q,d]*omega[j-32])
// omega[i] = 10000^(-i/32)
__global__ __launch_bounds__(256) void embed_kernel(const float* __restrict__ qpos,
                                                    float* __restrict__ qe) {
    int gid = blockIdx.x * 256 + threadIdx.x;   // grid exactly covers N_Q*192
    int q = gid / 192, c = gid - q * 192;
    int d = c >> 6, j = c & 63;
    int i = j & 31;
    float omega = expf(-(float)i * (9.210340371976184f / 32.0f)); // ln(10000)/32
    float arg = qpos[q * 3 + d] * omega;
    qe[gid] = (j < 32) ? sinf(arg) : cosf(arg);
}

// ---------------- xf = x @ proj_w + proj_b  (32768x192, K=192) ----------------
__global__ __launch_bounds__(256) void proj_kernel(const float* __restrict__ x,
                                                   const float* __restrict__ w,
                                                   const float* __restrict__ b,
                                                   float* __restrict__ xf) {
    __shared__ float xs[16 * 192];
    __shared__ float wc[16 * 192];
    const int t = threadIdx.x;
    const int r0 = blockIdx.x * 16;

    #pragma unroll
    for (int i = 0; i < 3; ++i) {                  // 768 float4s, 3 per thread
        int idx4 = t + 256 * i;
        int r = idx4 / 48, c4 = idx4 - r * 48;
        ((float4*)xs)[idx4] = ((const float4*)(x + (r0 + r) * 192))[c4];
    }
    const int e = t >> 4, o = t & 15;              // 16 rows x 16 col-threads
    float4 acc[3];
    #pragma unroll
    for (int jj = 0; jj < 3; ++jj)
        acc[jj] = *(const float4*)(b + o * 4 + 64 * jj);

    for (int kk = 0; kk < 192; kk += 16) {
        __syncthreads();
        #pragma unroll
        for (int i = 0; i < 3; ++i) {
            int idx4 = t + 256 * i;
            ((float4*)wc)[idx4] = ((const float4*)(w + kk * 192))[idx4];
        }
        __syncthreads();
        #pragma unroll
        for (int k = 0; k < 16; ++k) {
            float a = xs[e * 192 + kk + k];
            #pragma unroll
            for (int jj = 0; jj < 3; ++jj) {
                float4 w4 = *(const float4*)(wc + k * 192 + o * 4 + 64 * jj);
                acc[jj] = f4_fma(a, w4, acc[jj]);
            }
        }
    }
    #pragma unroll
    for (int jj = 0; jj < 3; ++jj)
        *(float4*)(xf + (r0 + e) * 192 + o * 4 + 64 * jj) = acc[jj];
}

// ---------------- fused edge MLP: gather -> 384->384->384->192 -> atomic segsum ----------------
__global__ __launch_bounds__(256) void edge_mlp_kernel(
    const float* __restrict__ xf, const float* __restrict__ qe,
    const int* __restrict__ edges,
    const float* __restrict__ w0, const float* __restrict__ b0,
    const float* __restrict__ w1, const float* __restrict__ b1,
    const float* __restrict__ w2, const float* __restrict__ b2,
    float* __restrict__ seg, float* __restrict__ cnt)
{
    __shared__ float h[16 * 384];      // 16 edges x 384 features
    __shared__ float wc[16 * 384];     // K-chunk of weights (16 x up-to-384)
    __shared__ int qi[16], gi[16];
    const int t = threadIdx.x;
    const int e0 = blockIdx.x * 16;

    if (t < 16) {
        int qv = edges[2 * (e0 + t)];
        int gv = edges[2 * (e0 + t) + 1];
        qi[t] = qv; gi[t] = gv;
        atomicAdd(&cnt[qv], 1.0f);
    }
    __syncthreads();

    // gather concat(xf[g], qe[q]) into h, float4-coalesced
    #pragma unroll
    for (int i = 0; i < 6; ++i) {                  // 1536 float4s, 6 per thread
        int idx4 = t + 256 * i;
        int e = idx4 / 96, c4 = idx4 - e * 96;
        float4 v;
        if (c4 < 48) v = ((const float4*)(xf + gi[e] * 192))[c4];
        else         v = ((const float4*)(qe + qi[e] * 192))[c4 - 48];
        ((float4*)h)[idx4] = v;
    }

    // layers 0 and 1: 384 -> 384, gelu, in-place in LDS
    const int eg = t >> 5, ot = t & 31;            // 8 edge-pairs x 32 col-threads
    const int ea = eg * 2, eb = ea + 1;
    #pragma unroll 1
    for (int L = 0; L < 2; ++L) {
        const float* __restrict__ W  = (L == 0) ? w0 : w1;
        const float* __restrict__ Bv = (L == 0) ? b0 : b1;
        float4 acc0[3], acc1[3];
        #pragma unroll
        for (int jj = 0; jj < 3; ++jj) {
            float4 bb = *(const float4*)(Bv + ot * 4 + 128 * jj);
            acc0[jj] = bb; acc1[jj] = bb;
        }
        for (int kk = 0; kk < 384; kk += 16) {
            __syncthreads();
            #pragma unroll
            for (int i = 0; i < 6; ++i) {          // contiguous 16x384 chunk
                int idx4 = t + 256 * i;
                ((float4*)wc)[idx4] = ((const float4*)(W + kk * 384))[idx4];
            }
            __syncthreads();
            #pragma unroll
            for (int k = 0; k < 16; ++k) {
                float a0 = h[ea * 384 + kk + k];   // LDS broadcast
                float a1 = h[eb * 384 + kk + k];
                #pragma unroll
                for (int jj = 0; jj < 3; ++jj) {
                    float4 w4 = *(const float4*)(wc + k * 384 + ot * 4 + 128 * jj);
                    acc0[jj] = f4_fma(a0, w4, acc0[jj]);
                    acc1[jj] = f4_fma(a1, w4, acc1[jj]);
                }
            }
        }
        __syncthreads();                           // all reads of h done
        #pragma unroll
        for (int jj = 0; jj < 3; ++jj) {
            int c = ot * 4 + 128 * jj;
            float4 v = acc0[jj];
            v.x = gelu_f(v.x); v.y = gelu_f(v.y); v.z = gelu_f(v.z); v.w = gelu_f(v.w);
            *(float4*)(h + ea * 384 + c) = v;
            v = acc1[jj];
            v.x = gelu_f(v.x); v.y = gelu_f(v.y); v.z = gelu_f(v.z); v.w = gelu_f(v.w);
            *(float4*)(h + eb * 384 + c) = v;
        }
        // next layer's first __syncthreads makes these writes visible
    }

    // layer 2: 384 -> 192, no activation, atomic segment-sum
    {
        const int e = t >> 4, o = t & 15;          // 16 edges x 16 col-threads
        float4 acc[3];
        #pragma unroll
        for (int jj = 0; jj < 3; ++jj)
            acc[jj] = *(const float4*)(b2 + o * 4 + 64 * jj);
        for (int kk = 0; kk < 384; kk += 16) {
            __syncthreads();
            #pragma unroll
            for (int i = 0; i < 3; ++i) {          // 16x192 chunk = 768 float4s
                int idx4 = t + 256 * i;
                ((float4*)wc)[idx4] = ((const float4*)(w2 + kk * 192))[idx4];
            }
            __syncthreads();
            #pragma unroll
            for (int k = 0; k < 16; ++k) {
                float a = h[e * 384 + kk + k];
                #pragma unroll
                for (int jj = 0; jj < 3; ++jj) {
                    float4 w4 = *(const float4*)(wc + k * 192 + o * 4 + 64 * jj);
                    acc[jj] = f4_fma(a, w4, acc[jj]);
                }
            }
        }
        float* dst = seg + qi[e] * 192;
        #pragma unroll
        for (int jj = 0; jj < 3; ++jj) {
            int c = o * 4 + 64 * jj;
            atomicAdd(dst + c + 0, acc[jj].x);
            atomicAdd(dst + c + 1, acc[jj].y);
            atomicAdd(dst + c + 2, acc[jj].z);
            atomicAdd(dst + c + 3, acc[jj].w);
        }
    }
}

// ---------------- head: m = seg/max(cnt,1); out = gelu(m@W0+b0)@W1+b1 ----------------
__global__ __launch_bounds__(256) void head_kernel(
    const float* __restrict__ seg, const float* __restrict__ cnt,
    const float* __restrict__ w0, const float* __restrict__ b0,
    const float* __restrict__ w1, const float* __restrict__ b1,
    float* __restrict__ out)
{
    __shared__ float ms[16 * 192];
    __shared__ float ps[16 * 192];
    __shared__ float wc[16 * 192];
    __shared__ float w1s[192 * 4];
    const int t = threadIdx.x;
    const int r0 = blockIdx.x * 16;

    #pragma unroll
    for (int i = 0; i < 3; ++i) {
        int idx4 = t + 256 * i;
        int r = idx4 / 48, c4 = idx4 - r * 48;
        float inv = 1.0f / fmaxf(cnt[r0 + r], 1.0f);
        float4 v = ((const float4*)(seg + (r0 + r) * 192))[c4];
        v.x *= inv; v.y *= inv; v.z *= inv; v.w *= inv;
        ((float4*)ms)[idx4] = v;
    }
    if (t < 192) ((float4*)w1s)[t] = ((const float4*)w1)[t];

    const int e = t >> 4, o = t & 15;
    float4 acc[3];
    #pragma unroll
    for (int jj = 0; jj < 3; ++jj)
        acc[jj] = *(const float4*)(b0 + o * 4 + 64 * jj);
    for (int kk = 0; kk < 192; kk += 16) {
        __syncthreads();
        #pragma unroll
        for (int i = 0; i < 3; ++i) {
            int idx4 = t + 256 * i;
            ((float4*)wc)[idx4] = ((const float4*)(w0 + kk * 192))[idx4];
        }
        __syncthreads();
        #pragma unroll
        for (int k = 0; k < 16; ++k) {
            float a = ms[e * 192 + kk + k];
            #pragma unroll
            for (int jj = 0; jj < 3; ++jj) {
                float4 w4 = *(const float4*)(wc + k * 192 + o * 4 + 64 * jj);
                acc[jj] = f4_fma(a, w4, acc[jj]);
            }
        }
    }
    __syncthreads();
    #pragma unroll
    for (int jj = 0; jj < 3; ++jj) {
        float4 v = acc[jj];
        v.x = gelu_f(v.x); v.y = gelu_f(v.y); v.z = gelu_f(v.z); v.w = gelu_f(v.w);
        *(float4*)(ps + e * 192 + o * 4 + 64 * jj) = v;
    }
    __syncthreads();
    if (t < 64) {
        int r = t >> 2, oo = t & 3;
        float a = b1[oo];
        for (int k = 0; k < 192; ++k)
            a = fmaf(ps[r * 192 + k], w1s[k * 4 + oo], a);
        out[(r0 + r) * 4 + oo] = a;
    }
}

extern "C" void kernel_launch(void* const* d_in, const int* in_sizes, int n_in,
                              void* d_out, int out_size, void* d_ws, size_t ws_size,
                              hipStream_t stream) {
    (void)in_sizes; (void)n_in; (void)out_size; (void)ws_size;
    const float* x       = (const float*)d_in[0];
    const float* qpos    = (const float*)d_in[1];
    const int*   edges   = (const int*)d_in[2];
    const float* proj_w  = (const float*)d_in[3];
    const float* proj_b  = (const float*)d_in[4];
    const float* msg0_w  = (const float*)d_in[5];
    const float* msg0_b  = (const float*)d_in[6];
    const float* msg1_w  = (const float*)d_in[7];
    const float* msg1_b  = (const float*)d_in[8];
    const float* msg2_w  = (const float*)d_in[9];
    const float* msg2_b  = (const float*)d_in[10];
    const float* pred0_w = (const float*)d_in[11];
    const float* pred0_b = (const float*)d_in[12];
    const float* pred1_w = (const float*)d_in[13];
    const float* pred1_b = (const float*)d_in[14];
    float* out = (float*)d_out;

    // ws layout: xf | qe | seg | cnt   (each feature buffer 32768*192*4 B)
    const size_t FB = (size_t)32768 * 192 * 4;   // 25,165,824 B
    char* ws = (char*)d_ws;
    float* xf  = (float*)(ws);
    float* qe  = (float*)(ws + FB);
    float* seg = (float*)(ws + 2 * FB);
    float* cnt = (float*)(ws + 3 * FB);

    hipMemsetAsync(seg, 0, FB + (size_t)32768 * 4, stream);   // seg + cnt
    embed_kernel<<<24576, 256, 0, stream>>>(qpos, qe);        // 32768*192/256
    proj_kernel<<<2048, 256, 0, stream>>>(x, proj_w, proj_b, xf);
    edge_mlp_kernel<<<16384, 256, 0, stream>>>(xf, qe, edges,
                                               msg0_w, msg0_b, msg1_w, msg1_b,
                                               msg2_w, msg2_b, seg, cnt);
    head_kernel<<<2048, 256, 0, stream>>>(seg, cnt, pred0_w, pred0_b,
                                          pred1_w, pred1_b, out);
}

// Round 2
// 688.946 us; speedup vs baseline: 6.9746x; 6.9746x over previous
//
#include <hip/hip_runtime.h>
#include <math.h>

// Problem constants
#define N_Q    32768
#define N_E    262144
// dims: IN=EMB=192, concat=384, 2*HID=384, BOT=192, PREDH=192, OUT=4

typedef _Float16 half8 __attribute__((ext_vector_type(8)));
typedef _Float16 half4v __attribute__((ext_vector_type(4)));
typedef float f32x4 __attribute__((ext_vector_type(4)));

__device__ __forceinline__ float gelu_f(float x) {
    return 0.5f * x * (1.0f + erff(x * 0.7071067811865475f));
}

__device__ __forceinline__ float4 f4_fma(float a, float4 w, float4 c) {
    c.x = fmaf(a, w.x, c.x); c.y = fmaf(a, w.y, c.y);
    c.z = fmaf(a, w.z, c.z); c.w = fmaf(a, w.w, c.w);
    return c;
}

// ---------------- sincos embedding -> f16 ----------------
__global__ __launch_bounds__(256) void embed_kernel(const float* __restrict__ qpos,
                                                    _Float16* __restrict__ qe) {
    int gid = blockIdx.x * 256 + threadIdx.x;   // covers N_Q*192
    int q = gid / 192, c = gid - q * 192;
    int d = c >> 6, j = c & 63;
    int i = j & 31;
    float omega = expf(-(float)i * (9.210340371976184f / 32.0f)); // ln(10000)/32
    float arg = qpos[q * 3 + d] * omega;
    qe[gid] = (_Float16)((j < 32) ? sinf(arg) : cosf(arg));
}

// ---------------- xf = x @ proj_w + proj_b -> f16 (32768x192, K=192) ----------------
__global__ __launch_bounds__(256) void proj_kernel(const float* __restrict__ x,
                                                   const float* __restrict__ w,
                                                   const float* __restrict__ b,
                                                   _Float16* __restrict__ xf) {
    __shared__ float xs[16 * 192];
    __shared__ float wc[16 * 192];
    const int t = threadIdx.x;
    const int r0 = blockIdx.x * 16;

    #pragma unroll
    for (int i = 0; i < 3; ++i) {
        int idx4 = t + 256 * i;
        int r = idx4 / 48, c4 = idx4 - r * 48;
        ((float4*)xs)[idx4] = ((const float4*)(x + (r0 + r) * 192))[c4];
    }
    const int e = t >> 4, o = t & 15;
    float4 acc[3];
    #pragma unroll
    for (int jj = 0; jj < 3; ++jj)
        acc[jj] = *(const float4*)(b + o * 4 + 64 * jj);

    for (int kk = 0; kk < 192; kk += 16) {
        __syncthreads();
        #pragma unroll
        for (int i = 0; i < 3; ++i) {
            int idx4 = t + 256 * i;
            ((float4*)wc)[idx4] = ((const float4*)(w + kk * 192))[idx4];
        }
        __syncthreads();
        #pragma unroll
        for (int k = 0; k < 16; ++k) {
            float a = xs[e * 192 + kk + k];
            #pragma unroll
            for (int jj = 0; jj < 3; ++jj) {
                float4 w4 = *(const float4*)(wc + k * 192 + o * 4 + 64 * jj);
                acc[jj] = f4_fma(a, w4, acc[jj]);
            }
        }
    }
    #pragma unroll
    for (int jj = 0; jj < 3; ++jj) {
        half4v hv;
        hv[0] = (_Float16)acc[jj].x; hv[1] = (_Float16)acc[jj].y;
        hv[2] = (_Float16)acc[jj].z; hv[3] = (_Float16)acc[jj].w;
        *(half4v*)(xf + (r0 + e) * 192 + o * 4 + 64 * jj) = hv;
    }
}

// ---------------- W[K][N] fp32 -> Wt[N][K] f16 ----------------
__global__ __launch_bounds__(256) void transpose_f16_kernel(const float* __restrict__ W,
                                                            _Float16* __restrict__ Wt,
                                                            int K, int N) {
    __shared__ float tile[32][33];
    const int k0 = blockIdx.x * 32, n0 = blockIdx.y * 32;
    const int t = threadIdx.x;
    const int tr = t >> 5, tc = t & 31;
    #pragma unroll
    for (int i = 0; i < 4; ++i) {
        int r = tr + i * 8;
        tile[r][tc] = W[(k0 + r) * N + n0 + tc];
    }
    __syncthreads();
    #pragma unroll
    for (int i = 0; i < 4; ++i) {
        int r = tr + i * 8;                       // n index within tile
        Wt[(size_t)(n0 + r) * K + k0 + tc] = (_Float16)tile[tc][r];
    }
}

// ---------------- fused edge MLP via f16 MFMA ----------------
// 64 edges/block, 4 waves; wave w owns N-slice [w*96, w*96+96) for layers 0/1,
// [w*48, w*48+48) for layer 2. A staged in LDS (padded), B read from L2 (Wt[n][k]).
#define PADK 392   // hA row stride in f16 elements (784 B, != 0 mod 128 B)

__global__ __launch_bounds__(256, 2) void edge_mlp_kernel(
    const _Float16* __restrict__ xf, const _Float16* __restrict__ qe,
    const int* __restrict__ edges,
    const _Float16* __restrict__ Wt0, const float* __restrict__ b0,
    const _Float16* __restrict__ Wt1, const float* __restrict__ b1,
    const _Float16* __restrict__ Wt2, const float* __restrict__ b2,
    float* __restrict__ seg, float* __restrict__ cnt)
{
    __shared__ _Float16 hA[64 * PADK];   // 50176 B; aliased as f32 h2[64][192] later
    __shared__ int qi[64], gi[64];
    float* h2 = (float*)hA;

    const int t = threadIdx.x;
    const int e0 = blockIdx.x * 64;
    const int lane = t & 63;
    const int w = t >> 6;
    const int ln = lane & 15;            // MFMA n / m low index
    const int lq = lane >> 4;            // quad: k-offset = lq*8, C-row = lq*4+r

    if (t < 64) {
        qi[t] = edges[2 * (e0 + t)];
        gi[t] = edges[2 * (e0 + t) + 1];
    }
    __syncthreads();

    // ---- gather concat(xf[g], qe[q]) into padded LDS, 16B chunks ----
    #pragma unroll
    for (int i = 0; i < 12; ++i) {
        int idx = t + 256 * i;                       // 3072 chunks
        int m = idx / 48, c = idx - m * 48;
        const half8* src = (c < 24) ? ((const half8*)(xf + gi[m] * 192) + c)
                                    : ((const half8*)(qe + qi[m] * 192) + (c - 24));
        *(half8*)(hA + m * PADK + c * 8) = *src;
    }
    __syncthreads();

    // ---- layers 0,1: 384 -> 384, gelu, in-place ----
    #pragma unroll 1
    for (int L = 0; L < 2; ++L) {
        const _Float16* __restrict__ Wt = L ? Wt1 : Wt0;
        const float* __restrict__ bias = L ? b1 : b0;
        const int n0 = w * 96;

        f32x4 acc[4][6];
        #pragma unroll
        for (int nt = 0; nt < 6; ++nt) {
            float bv = bias[n0 + nt * 16 + ln];
            #pragma unroll
            for (int mt = 0; mt < 4; ++mt)
                acc[mt][nt] = (f32x4){bv, bv, bv, bv};
        }
        #pragma unroll 2
        for (int ks = 0; ks < 12; ++ks) {
            half8 a[4], bf[6];
            #pragma unroll
            for (int mt = 0; mt < 4; ++mt)
                a[mt] = *(const half8*)(hA + (mt * 16 + ln) * PADK + ks * 32 + lq * 8);
            #pragma unroll
            for (int nt = 0; nt < 6; ++nt)
                bf[nt] = *(const half8*)(Wt + (size_t)(n0 + nt * 16 + ln) * 384 + ks * 32 + lq * 8);
            #pragma unroll
            for (int nt = 0; nt < 6; ++nt)
                #pragma unroll
                for (int mt = 0; mt < 4; ++mt)
                    acc[mt][nt] = __builtin_amdgcn_mfma_f32_16x16x32_f16(a[mt], bf[nt], acc[mt][nt], 0, 0, 0);
        }
        __syncthreads();   // all waves done reading hA
        #pragma unroll
        for (int mt = 0; mt < 4; ++mt)
            #pragma unroll
            for (int nt = 0; nt < 6; ++nt)
                #pragma unroll
                for (int r = 0; r < 4; ++r) {
                    int m = mt * 16 + lq * 4 + r;
                    int n = n0 + nt * 16 + ln;
                    hA[m * PADK + n] = (_Float16)gelu_f(acc[mt][nt][r]);
                }
        __syncthreads();
    }

    // ---- layer 2: 384 -> 192, no activation ----
    {
        const int n0 = w * 48;
        f32x4 acc[4][3];
        #pragma unroll
        for (int nt = 0; nt < 3; ++nt) {
            float bv = b2[n0 + nt * 16 + ln];
            #pragma unroll
            for (int mt = 0; mt < 4; ++mt)
                acc[mt][nt] = (f32x4){bv, bv, bv, bv};
        }
        #pragma unroll 2
        for (int ks = 0; ks < 12; ++ks) {
            half8 a[4], bf[3];
            #pragma unroll
            for (int mt = 0; mt < 4; ++mt)
                a[mt] = *(const half8*)(hA + (mt * 16 + ln) * PADK + ks * 32 + lq * 8);
            #pragma unroll
            for (int nt = 0; nt < 3; ++nt)
                bf[nt] = *(const half8*)(Wt2 + (size_t)(n0 + nt * 16 + ln) * 384 + ks * 32 + lq * 8);
            #pragma unroll
            for (int nt = 0; nt < 3; ++nt)
                #pragma unroll
                for (int mt = 0; mt < 4; ++mt)
                    acc[mt][nt] = __builtin_amdgcn_mfma_f32_16x16x32_f16(a[mt], bf[nt], acc[mt][nt], 0, 0, 0);
        }
        __syncthreads();   // all waves done reading hA; safe to overwrite as h2
        #pragma unroll
        for (int mt = 0; mt < 4; ++mt)
            #pragma unroll
            for (int nt = 0; nt < 3; ++nt)
                #pragma unroll
                for (int r = 0; r < 4; ++r) {
                    int m = mt * 16 + lq * 4 + r;
                    int n = n0 + nt * 16 + ln;
                    h2[m * 192 + n] = acc[mt][nt][r];
                }
        __syncthreads();
    }

    // ---- segment reduce within block (qidx sorted), then atomics ----
    if (t < 192) {
        float a = 0.0f;
        for (int m = 0; m < 64; ++m) {
            a += h2[m * 192 + t];
            if (m == 63 || qi[m + 1] != qi[m]) {
                atomicAdd(&seg[(size_t)qi[m] * 192 + t], a);
                a = 0.0f;
            }
        }
    } else if (t == 192) {
        float run = 1.0f;
        for (int m = 1; m < 64; ++m) {
            if (qi[m] != qi[m - 1]) { atomicAdd(&cnt[qi[m - 1]], run); run = 1.0f; }
            else run += 1.0f;
        }
        atomicAdd(&cnt[qi[63]], run);
    }
}

// ---------------- head: m = seg/max(cnt,1); out = gelu(m@W0+b0)@W1+b1 ----------------
__global__ __launch_bounds__(256) void head_kernel(
    const float* __restrict__ seg, const float* __restrict__ cnt,
    const float* __restrict__ w0, const float* __restrict__ b0,
    const float* __restrict__ w1, const float* __restrict__ b1,
    float* __restrict__ out)
{
    __shared__ float ms[16 * 192];
    __shared__ float ps[16 * 192];
    __shared__ float wc[16 * 192];
    __shared__ float w1s[192 * 4];
    const int t = threadIdx.x;
    const int r0 = blockIdx.x * 16;

    #pragma unroll
    for (int i = 0; i < 3; ++i) {
        int idx4 = t + 256 * i;
        int r = idx4 / 48, c4 = idx4 - r * 48;
        float inv = 1.0f / fmaxf(cnt[r0 + r], 1.0f);
        float4 v = ((const float4*)(seg + (size_t)(r0 + r) * 192))[c4];
        v.x *= inv; v.y *= inv; v.z *= inv; v.w *= inv;
        ((float4*)ms)[idx4] = v;
    }
    if (t < 192) ((float4*)w1s)[t] = ((const float4*)w1)[t];

    const int e = t >> 4, o = t & 15;
    float4 acc[3];
    #pragma unroll
    for (int jj = 0; jj < 3; ++jj)
        acc[jj] = *(const float4*)(b0 + o * 4 + 64 * jj);
    for (int kk = 0; kk < 192; kk += 16) {
        __syncthreads();
        #pragma unroll
        for (int i = 0; i < 3; ++i) {
            int idx4 = t + 256 * i;
            ((float4*)wc)[idx4] = ((const float4*)(w0 + kk * 192))[idx4];
        }
        __syncthreads();
        #pragma unroll
        for (int k = 0; k < 16; ++k) {
            float a = ms[e * 192 + kk + k];
            #pragma unroll
            for (int jj = 0; jj < 3; ++jj) {
                float4 w4 = *(const float4*)(wc + k * 192 + o * 4 + 64 * jj);
                acc[jj] = f4_fma(a, w4, acc[jj]);
            }
        }
    }
    __syncthreads();
    #pragma unroll
    for (int jj = 0; jj < 3; ++jj) {
        float4 v = acc[jj];
        v.x = gelu_f(v.x); v.y = gelu_f(v.y); v.z = gelu_f(v.z); v.w = gelu_f(v.w);
        *(float4*)(ps + e * 192 + o * 4 + 64 * jj) = v;
    }
    __syncthreads();
    if (t < 64) {
        int r = t >> 2, oo = t & 3;
        float a = b1[oo];
        for (int k = 0; k < 192; ++k)
            a = fmaf(ps[r * 192 + k], w1s[k * 4 + oo], a);
        out[(r0 + r) * 4 + oo] = a;
    }
}

extern "C" void kernel_launch(void* const* d_in, const int* in_sizes, int n_in,
                              void* d_out, int out_size, void* d_ws, size_t ws_size,
                              hipStream_t stream) {
    (void)in_sizes; (void)n_in; (void)out_size; (void)ws_size;
    const float* x       = (const float*)d_in[0];
    const float* qpos    = (const float*)d_in[1];
    const int*   edges   = (const int*)d_in[2];
    const float* proj_w  = (const float*)d_in[3];
    const float* proj_b  = (const float*)d_in[4];
    const float* msg0_w  = (const float*)d_in[5];
    const float* msg0_b  = (const float*)d_in[6];
    const float* msg1_w  = (const float*)d_in[7];
    const float* msg1_b  = (const float*)d_in[8];
    const float* msg2_w  = (const float*)d_in[9];
    const float* msg2_b  = (const float*)d_in[10];
    const float* pred0_w = (const float*)d_in[11];
    const float* pred0_b = (const float*)d_in[12];
    const float* pred1_w = (const float*)d_in[13];
    const float* pred1_b = (const float*)d_in[14];
    float* out = (float*)d_out;

    // ws layout (bytes):
    //  xf f16: 32768*192*2 = 12582912       @ 0
    //  qe f16: 12582912                     @ 12582912
    //  seg f32: 32768*192*4 = 25165824      @ 25165824
    //  cnt f32: 131072                      @ 50331648
    //  Wt0 f16: 384*384*2 = 294912          @ 50462720
    //  Wt1 f16: 294912                      @ 50757632
    //  Wt2 f16: 192*384*2 = 147456          @ 51052544
    char* ws = (char*)d_ws;
    _Float16* xf  = (_Float16*)(ws);
    _Float16* qe  = (_Float16*)(ws + 12582912);
    float*    seg = (float*)(ws + 25165824);
    float*    cnt = (float*)(ws + 50331648);
    _Float16* Wt0 = (_Float16*)(ws + 50462720);
    _Float16* Wt1 = (_Float16*)(ws + 50757632);
    _Float16* Wt2 = (_Float16*)(ws + 51052544);

    hipMemsetAsync(seg, 0, 25165824 + 131072, stream);   // seg + cnt
    embed_kernel<<<24576, 256, 0, stream>>>(qpos, qe);
    proj_kernel<<<2048, 256, 0, stream>>>(x, proj_w, proj_b, xf);
    transpose_f16_kernel<<<dim3(12, 12), 256, 0, stream>>>(msg0_w, Wt0, 384, 384);
    transpose_f16_kernel<<<dim3(12, 12), 256, 0, stream>>>(msg1_w, Wt1, 384, 384);
    transpose_f16_kernel<<<dim3(12, 6),  256, 0, stream>>>(msg2_w, Wt2, 384, 192);
    edge_mlp_kernel<<<4096, 256, 0, stream>>>(xf, qe, edges,
                                              Wt0, msg0_b, Wt1, msg1_b, Wt2, msg2_b,
                                              seg, cnt);
    head_kernel<<<2048, 256, 0, stream>>>(seg, cnt, pred0_w, pred0_b,
                                          pred1_w, pred1_b, out);
}

// Round 3
// 600.639 us; speedup vs baseline: 8.0000x; 1.1470x over previous
//
#include <hip/hip_runtime.h>
#include <math.h>

// Problem constants
#define N_Q    32768
#define N_E    262144
// dims: IN=EMB=192, concat=384, 2*HID=384, BOT=192, PREDH=192, OUT=4

typedef _Float16 half8 __attribute__((ext_vector_type(8)));
typedef _Float16 half4v __attribute__((ext_vector_type(4)));
typedef float f32x4 __attribute__((ext_vector_type(4)));

// Abramowitz-Stegun 7.1.26 erf (|eps| <= 1.5e-7), branchless gelu.
// gelu(x) = 0.5x(1+erf(x/sqrt2)) = 0.5x + 0.5|x|*erf(|x|/sqrt2)
__device__ __forceinline__ float gelu_f(float x) {
    float ax = fabsf(x);
    float z = ax * 0.7071067811865476f;
    float t = 1.0f / fmaf(0.3275911f, z, 1.0f);
    float poly = t * fmaf(t, fmaf(t, fmaf(t, fmaf(t, 1.061405429f, -1.453152027f),
                                          1.421413741f), -0.284496736f), 0.254829592f);
    float u = fmaf(-poly, __expf(-z * z), 1.0f);
    return fmaf(0.5f * ax, u, 0.5f * x);
}

// ---------------- sincos embedding -> f16 ----------------
__global__ __launch_bounds__(256) void embed_kernel(const float* __restrict__ qpos,
                                                    _Float16* __restrict__ qe) {
    int gid = blockIdx.x * 256 + threadIdx.x;   // covers N_Q*192
    int q = gid / 192, c = gid - q * 192;
    int d = c >> 6, j = c & 63;
    int i = j & 31;
    float omega = expf(-(float)i * (9.210340371976184f / 32.0f)); // ln(10000)/32
    float arg = qpos[q * 3 + d] * omega;
    qe[gid] = (_Float16)((j < 32) ? sinf(arg) : cosf(arg));
}

// ---------------- W[K][N] fp32 -> Wt[N][K] f16 ----------------
__global__ __launch_bounds__(256) void transpose_f16_kernel(const float* __restrict__ W,
                                                            _Float16* __restrict__ Wt,
                                                            int K, int N) {
    __shared__ float tile[32][33];
    const int k0 = blockIdx.x * 32, n0 = blockIdx.y * 32;
    const int t = threadIdx.x;
    const int tr = t >> 5, tc = t & 31;
    #pragma unroll
    for (int i = 0; i < 4; ++i) {
        int r = tr + i * 8;
        tile[r][tc] = W[(k0 + r) * N + n0 + tc];
    }
    __syncthreads();
    #pragma unroll
    for (int i = 0; i < 4; ++i) {
        int r = tr + i * 8;                       // n index within tile
        Wt[(size_t)(n0 + r) * K + k0 + tc] = (_Float16)tile[tc][r];
    }
}

// ---------------- proj: xf = f16(x @ proj_w + proj_b), via MFMA ----------------
// 64 rows/block, 4 waves; wave owns 48-col N-slice. K=192.
#define PK 200   // hA row stride (f16), 400 B

__global__ __launch_bounds__(256, 2) void proj_mfma_kernel(
    const float* __restrict__ x, const _Float16* __restrict__ Wt,
    const float* __restrict__ bias, _Float16* __restrict__ xf)
{
    __shared__ _Float16 hA[64 * PK];   // 25600 B
    const int t = threadIdx.x;
    const int r0 = blockIdx.x * 64;
    const int lane = t & 63;
    const int w = t >> 6;
    const int ln = lane & 15, lq = lane >> 4;

    #pragma unroll
    for (int i = 0; i < 12; ++i) {                 // 3072 float4s
        int idx = t + 256 * i;
        int r = idx / 48, c4 = idx - r * 48;
        float4 v = ((const float4*)(x + (size_t)(r0 + r) * 192))[c4];
        half4v hv; hv[0] = (_Float16)v.x; hv[1] = (_Float16)v.y;
        hv[2] = (_Float16)v.z; hv[3] = (_Float16)v.w;
        *(half4v*)(hA + r * PK + c4 * 4) = hv;
    }
    __syncthreads();

    const int n0 = w * 48;
    f32x4 acc[4][3];
    #pragma unroll
    for (int nt = 0; nt < 3; ++nt) {
        float bv = bias[n0 + nt * 16 + ln];
        #pragma unroll
        for (int mt = 0; mt < 4; ++mt) acc[mt][nt] = (f32x4){bv, bv, bv, bv};
    }
    #pragma unroll
    for (int ks = 0; ks < 6; ++ks) {
        half8 a[4], bf[3];
        #pragma unroll
        for (int mt = 0; mt < 4; ++mt)
            a[mt] = *(const half8*)(hA + (mt * 16 + ln) * PK + ks * 32 + lq * 8);
        #pragma unroll
        for (int nt = 0; nt < 3; ++nt)
            bf[nt] = *(const half8*)(Wt + (size_t)(n0 + nt * 16 + ln) * 192 + ks * 32 + lq * 8);
        #pragma unroll
        for (int nt = 0; nt < 3; ++nt)
            #pragma unroll
            for (int mt = 0; mt < 4; ++mt)
                acc[mt][nt] = __builtin_amdgcn_mfma_f32_16x16x32_f16(a[mt], bf[nt], acc[mt][nt], 0, 0, 0);
    }
    #pragma unroll
    for (int mt = 0; mt < 4; ++mt)
        #pragma unroll
        for (int nt = 0; nt < 3; ++nt)
            #pragma unroll
            for (int r = 0; r < 4; ++r) {
                int m = mt * 16 + lq * 4 + r;
                int n = n0 + nt * 16 + ln;
                xf[(size_t)(r0 + m) * 192 + n] = (_Float16)acc[mt][nt][r];
            }
}

// ---------------- fused edge MLP via f16 MFMA, pipelined B ----------------
#define PADK 392   // hA row stride in f16 elements (784 B)

__global__ __launch_bounds__(256, 2) void edge_mlp_kernel(
    const _Float16* __restrict__ xf, const _Float16* __restrict__ qe,
    const int* __restrict__ edges,
    const _Float16* __restrict__ Wt0, const float* __restrict__ b0,
    const _Float16* __restrict__ Wt1, const float* __restrict__ b1,
    const _Float16* __restrict__ Wt2, const float* __restrict__ b2,
    float* __restrict__ seg, float* __restrict__ cnt)
{
    __shared__ _Float16 hA[64 * PADK];   // 50176 B; aliased as f32 h2[64][192] later
    __shared__ int qi[64], gi[64];
    float* h2 = (float*)hA;

    const int t = threadIdx.x;
    const int e0 = blockIdx.x * 64;
    const int lane = t & 63;
    const int w = t >> 6;
    const int ln = lane & 15;            // MFMA n / m low index
    const int lq = lane >> 4;            // quad: k-offset = lq*8, C-row = lq*4+r

    if (t < 64) {
        qi[t] = edges[2 * (e0 + t)];
        gi[t] = edges[2 * (e0 + t) + 1];
    }
    __syncthreads();

    // ---- gather concat(xf[g], qe[q]) into padded LDS, 16B chunks ----
    #pragma unroll
    for (int i = 0; i < 12; ++i) {
        int idx = t + 256 * i;                       // 3072 chunks
        int m = idx / 48, c = idx - m * 48;
        const half8* src = (c < 24) ? ((const half8*)(xf + (size_t)gi[m] * 192) + c)
                                    : ((const half8*)(qe + (size_t)qi[m] * 192) + (c - 24));
        *(half8*)(hA + m * PADK + c * 8) = *src;
    }
    __syncthreads();

    // ---- layers 0,1: 384 -> 384, gelu, in-place ----
    #pragma unroll 1
    for (int L = 0; L < 2; ++L) {
        const _Float16* __restrict__ Wt = L ? Wt1 : Wt0;
        const float* __restrict__ bias = L ? b1 : b0;
        const int n0 = w * 96;

        const _Float16* wptr[6];
        #pragma unroll
        for (int nt = 0; nt < 6; ++nt)
            wptr[nt] = Wt + (size_t)(n0 + nt * 16 + ln) * 384 + lq * 8;

        f32x4 acc[4][6];
        #pragma unroll
        for (int nt = 0; nt < 6; ++nt) {
            float bv = bias[n0 + nt * 16 + ln];
            #pragma unroll
            for (int mt = 0; mt < 4; ++mt)
                acc[mt][nt] = (f32x4){bv, bv, bv, bv};
        }

        half8 bf[2][6];
        #pragma unroll
        for (int nt = 0; nt < 6; ++nt) bf[0][nt] = *(const half8*)(wptr[nt]);

        #pragma unroll
        for (int ks = 0; ks < 12; ++ks) {
            const int cur = ks & 1, nxt = cur ^ 1;
            half8 a[4];
            #pragma unroll
            for (int mt = 0; mt < 4; ++mt)
                a[mt] = *(const half8*)(hA + (mt * 16 + ln) * PADK + ks * 32 + lq * 8);
            if (ks < 11) {
                #pragma unroll
                for (int nt = 0; nt < 6; ++nt)
                    bf[nxt][nt] = *(const half8*)(wptr[nt] + (ks + 1) * 32);
            }
            #pragma unroll
            for (int nt = 0; nt < 6; ++nt)
                #pragma unroll
                for (int mt = 0; mt < 4; ++mt)
                    acc[mt][nt] = __builtin_amdgcn_mfma_f32_16x16x32_f16(a[mt], bf[cur][nt], acc[mt][nt], 0, 0, 0);
        }
        __syncthreads();   // all waves done reading hA
        #pragma unroll
        for (int mt = 0; mt < 4; ++mt)
            #pragma unroll
            for (int nt = 0; nt < 6; ++nt)
                #pragma unroll
                for (int r = 0; r < 4; ++r) {
                    int m = mt * 16 + lq * 4 + r;
                    int n = n0 + nt * 16 + ln;
                    hA[m * PADK + n] = (_Float16)gelu_f(acc[mt][nt][r]);
                }
        __syncthreads();
    }

    // ---- layer 2: 384 -> 192, no activation ----
    {
        const int n0 = w * 48;
        const _Float16* wptr[3];
        #pragma unroll
        for (int nt = 0; nt < 3; ++nt)
            wptr[nt] = Wt2 + (size_t)(n0 + nt * 16 + ln) * 384 + lq * 8;

        f32x4 acc[4][3];
        #pragma unroll
        for (int nt = 0; nt < 3; ++nt) {
            float bv = b2[n0 + nt * 16 + ln];
            #pragma unroll
            for (int mt = 0; mt < 4; ++mt)
                acc[mt][nt] = (f32x4){bv, bv, bv, bv};
        }
        half8 bf[2][3];
        #pragma unroll
        for (int nt = 0; nt < 3; ++nt) bf[0][nt] = *(const half8*)(wptr[nt]);

        #pragma unroll
        for (int ks = 0; ks < 12; ++ks) {
            const int cur = ks & 1, nxt = cur ^ 1;
            half8 a[4];
            #pragma unroll
            for (int mt = 0; mt < 4; ++mt)
                a[mt] = *(const half8*)(hA + (mt * 16 + ln) * PADK + ks * 32 + lq * 8);
            if (ks < 11) {
                #pragma unroll
                for (int nt = 0; nt < 3; ++nt)
                    bf[nxt][nt] = *(const half8*)(wptr[nt] + (ks + 1) * 32);
            }
            #pragma unroll
            for (int nt = 0; nt < 3; ++nt)
                #pragma unroll
                for (int mt = 0; mt < 4; ++mt)
                    acc[mt][nt] = __builtin_amdgcn_mfma_f32_16x16x32_f16(a[mt], bf[cur][nt], acc[mt][nt], 0, 0, 0);
        }
        __syncthreads();   // all waves done reading hA; safe to overwrite as h2
        #pragma unroll
        for (int mt = 0; mt < 4; ++mt)
            #pragma unroll
            for (int nt = 0; nt < 3; ++nt)
                #pragma unroll
                for (int r = 0; r < 4; ++r) {
                    int m = mt * 16 + lq * 4 + r;
                    int n = n0 + nt * 16 + ln;
                    h2[m * 192 + n] = acc[mt][nt][r];
                }
        __syncthreads();
    }

    // ---- segment reduce within block (qidx sorted), then atomics ----
    if (t < 192) {
        float a = 0.0f;
        for (int m = 0; m < 64; ++m) {
            a += h2[m * 192 + t];
            if (m == 63 || qi[m + 1] != qi[m]) {
                atomicAdd(&seg[(size_t)qi[m] * 192 + t], a);
                a = 0.0f;
            }
        }
    } else if (t == 192) {
        float run = 1.0f;
        for (int m = 1; m < 64; ++m) {
            if (qi[m] != qi[m - 1]) { atomicAdd(&cnt[qi[m - 1]], run); run = 1.0f; }
            else run += 1.0f;
        }
        atomicAdd(&cnt[qi[63]], run);
    }
}

// ---------------- head: m = seg/max(cnt,1); out = gelu(m@W0+b0)@W1+b1 ----------------
// 64 rows/block; layer0 via MFMA (f16), layer1 (192->4) fp32 from LDS.
#define PSK 196   // ps row stride (f32), breaks 192%32==0 conflict

__global__ __launch_bounds__(256, 2) void head_kernel(
    const float* __restrict__ seg, const float* __restrict__ cnt,
    const _Float16* __restrict__ Wt0, const float* __restrict__ b0,
    const float* __restrict__ w1, const float* __restrict__ b1,
    float* __restrict__ out)
{
    __shared__ _Float16 hA[64 * PK];     // 25600 B
    __shared__ float ps[64 * PSK];       // 50176 B
    __shared__ float w1s[192 * 4];
    __shared__ float invc[64];
    const int t = threadIdx.x;
    const int r0 = blockIdx.x * 64;
    const int lane = t & 63;
    const int w = t >> 6;
    const int ln = lane & 15, lq = lane >> 4;

    if (t < 64) invc[t] = 1.0f / fmaxf(cnt[r0 + t], 1.0f);
    if (t < 192) ((float4*)w1s)[t] = ((const float4*)w1)[t];
    __syncthreads();

    #pragma unroll
    for (int i = 0; i < 12; ++i) {
        int idx = t + 256 * i;
        int r = idx / 48, c4 = idx - r * 48;
        float inv = invc[r];
        float4 v = ((const float4*)(seg + (size_t)(r0 + r) * 192))[c4];
        half4v hv; hv[0] = (_Float16)(v.x * inv); hv[1] = (_Float16)(v.y * inv);
        hv[2] = (_Float16)(v.z * inv); hv[3] = (_Float16)(v.w * inv);
        *(half4v*)(hA + r * PK + c4 * 4) = hv;
    }
    __syncthreads();

    const int n0 = w * 48;
    f32x4 acc[4][3];
    #pragma unroll
    for (int nt = 0; nt < 3; ++nt) {
        float bv = b0[n0 + nt * 16 + ln];
        #pragma unroll
        for (int mt = 0; mt < 4; ++mt) acc[mt][nt] = (f32x4){bv, bv, bv, bv};
    }
    #pragma unroll
    for (int ks = 0; ks < 6; ++ks) {
        half8 a[4], bf[3];
        #pragma unroll
        for (int mt = 0; mt < 4; ++mt)
            a[mt] = *(const half8*)(hA + (mt * 16 + ln) * PK + ks * 32 + lq * 8);
        #pragma unroll
        for (int nt = 0; nt < 3; ++nt)
            bf[nt] = *(const half8*)(Wt0 + (size_t)(n0 + nt * 16 + ln) * 192 + ks * 32 + lq * 8);
        #pragma unroll
        for (int nt = 0; nt < 3; ++nt)
            #pragma unroll
            for (int mt = 0; mt < 4; ++mt)
                acc[mt][nt] = __builtin_amdgcn_mfma_f32_16x16x32_f16(a[mt], bf[nt], acc[mt][nt], 0, 0, 0);
    }
    #pragma unroll
    for (int mt = 0; mt < 4; ++mt)
        #pragma unroll
        for (int nt = 0; nt < 3; ++nt)
            #pragma unroll
            for (int r = 0; r < 4; ++r) {
                int m = mt * 16 + lq * 4 + r;
                int n = n0 + nt * 16 + ln;
                ps[m * PSK + n] = gelu_f(acc[mt][nt][r]);
            }
    __syncthreads();

    // layer1: 192 -> 4, one thread per (row, out-col)
    {
        int r = t >> 2, oo = t & 3;
        float a = b1[oo];
        for (int k = 0; k < 192; ++k)
            a = fmaf(ps[r * PSK + k], w1s[k * 4 + oo], a);
        out[(size_t)(r0 + r) * 4 + oo] = a;
    }
}

extern "C" void kernel_launch(void* const* d_in, const int* in_sizes, int n_in,
                              void* d_out, int out_size, void* d_ws, size_t ws_size,
                              hipStream_t stream) {
    (void)in_sizes; (void)n_in; (void)out_size; (void)ws_size;
    const float* x       = (const float*)d_in[0];
    const float* qpos    = (const float*)d_in[1];
    const int*   edges   = (const int*)d_in[2];
    const float* proj_w  = (const float*)d_in[3];
    const float* proj_b  = (const float*)d_in[4];
    const float* msg0_w  = (const float*)d_in[5];
    const float* msg0_b  = (const float*)d_in[6];
    const float* msg1_w  = (const float*)d_in[7];
    const float* msg1_b  = (const float*)d_in[8];
    const float* msg2_w  = (const float*)d_in[9];
    const float* msg2_b  = (const float*)d_in[10];
    const float* pred0_w = (const float*)d_in[11];
    const float* pred0_b = (const float*)d_in[12];
    const float* pred1_w = (const float*)d_in[13];
    const float* pred1_b = (const float*)d_in[14];
    float* out = (float*)d_out;

    // ws layout (bytes):
    //  xf  f16: 12582912                    @ 0
    //  qe  f16: 12582912                    @ 12582912
    //  seg f32: 25165824                    @ 25165824
    //  cnt f32: 131072                      @ 50331648
    //  Wt0 f16: 294912                      @ 50462720
    //  Wt1 f16: 294912                      @ 50757632
    //  Wt2 f16: 147456                      @ 51052544
    //  WtP f16 (proj_w^T):  73728           @ 51200000
    //  WtH f16 (pred0_w^T): 73728           @ 51273728
    char* ws = (char*)d_ws;
    _Float16* xf  = (_Float16*)(ws);
    _Float16* qe  = (_Float16*)(ws + 12582912);
    float*    seg = (float*)(ws + 25165824);
    float*    cnt = (float*)(ws + 50331648);
    _Float16* Wt0 = (_Float16*)(ws + 50462720);
    _Float16* Wt1 = (_Float16*)(ws + 50757632);
    _Float16* Wt2 = (_Float16*)(ws + 51052544);
    _Float16* WtP = (_Float16*)(ws + 51200000);
    _Float16* WtH = (_Float16*)(ws + 51273728);

    hipMemsetAsync(seg, 0, 25165824 + 131072, stream);   // seg + cnt
    embed_kernel<<<24576, 256, 0, stream>>>(qpos, qe);
    transpose_f16_kernel<<<dim3(6, 6),   256, 0, stream>>>(proj_w,  WtP, 192, 192);
    transpose_f16_kernel<<<dim3(12, 12), 256, 0, stream>>>(msg0_w, Wt0, 384, 384);
    transpose_f16_kernel<<<dim3(12, 12), 256, 0, stream>>>(msg1_w, Wt1, 384, 384);
    transpose_f16_kernel<<<dim3(12, 6),  256, 0, stream>>>(msg2_w, Wt2, 384, 192);
    transpose_f16_kernel<<<dim3(6, 6),   256, 0, stream>>>(pred0_w, WtH, 192, 192);
    proj_mfma_kernel<<<512, 256, 0, stream>>>(x, WtP, proj_b, xf);
    edge_mlp_kernel<<<4096, 256, 0, stream>>>(xf, qe, edges,
                                              Wt0, msg0_b, Wt1, msg1_b, Wt2, msg2_b,
                                              seg, cnt);
    head_kernel<<<512, 256, 0, stream>>>(seg, cnt, WtH, pred0_b,
                                         pred1_w, pred1_b, out);
}

// Round 4
// 406.115 us; speedup vs baseline: 11.8319x; 1.4790x over previous
//
#include <hip/hip_runtime.h>
#include <math.h>

// Problem constants
#define N_Q    32768
#define N_E    262144
// dims: IN=EMB=192, concat=384, 2*HID=384, BOT=192, PREDH=192, OUT=4

typedef _Float16 half8 __attribute__((ext_vector_type(8)));
typedef _Float16 half4v __attribute__((ext_vector_type(4)));
typedef float f32x4 __attribute__((ext_vector_type(4)));

// Abramowitz-Stegun 7.1.26 erf (|eps|<=1.5e-7), branchless; rcp via HW (1 ulp).
__device__ __forceinline__ float gelu_f(float x) {
    float ax = fabsf(x);
    float z = ax * 0.7071067811865476f;
    float t = __builtin_amdgcn_rcpf(fmaf(0.3275911f, z, 1.0f));
    float poly = t * fmaf(t, fmaf(t, fmaf(t, fmaf(t, 1.061405429f, -1.453152027f),
                                          1.421413741f), -0.284496736f), 0.254829592f);
    float u = fmaf(-poly, __expf(-z * z), 1.0f);
    return fmaf(0.5f * ax, u, 0.5f * x);
}

// ---------------- sincos embedding -> f16 ----------------
__global__ __launch_bounds__(256) void embed_kernel(const float* __restrict__ qpos,
                                                    _Float16* __restrict__ qe) {
    int gid = blockIdx.x * 256 + threadIdx.x;   // covers N_Q*192
    int q = gid / 192, c = gid - q * 192;
    int d = c >> 6, j = c & 63;
    int i = j & 31;
    float omega = expf(-(float)i * (9.210340371976184f / 32.0f)); // ln(10000)/32
    float arg = qpos[q * 3 + d] * omega;
    qe[gid] = (_Float16)((j < 32) ? sinf(arg) : cosf(arg));
}

// ---------------- pack W[K][N] fp32 -> fragment-order f16 ----------------
// Output: per (n_tile, ks) a 1KB block; lane l holds B[k=ks*32+(l>>4)*8+j][n=n_tile*16+(l&15)]
// at halves offset blk*512 + l*8.  blk = n_tile*(K/32) + ks.
__global__ __launch_bounds__(256) void pack_w_kernel(const float* __restrict__ W,
                                                     _Float16* __restrict__ Wp,
                                                     int K, int N) {
    int u = blockIdx.x * 256 + threadIdx.x;        // one half8 per thread
    if (u * 8 >= K * N) return;
    int l = u & 63, blk = u >> 6;
    int nks = K >> 5;
    int ntile = blk / nks, ks = blk - ntile * nks;
    int n = ntile * 16 + (l & 15);
    int k0 = ks * 32 + (l >> 4) * 8;
    half8 v;
    #pragma unroll
    for (int j = 0; j < 8; ++j) v[j] = (_Float16)W[(size_t)(k0 + j) * N + n];
    *(half8*)(Wp + (size_t)u * 8) = v;
}

// ---------------- proj: xf = f16(x @ proj_w + proj_b), via MFMA ----------------
#define PK 200   // hA row stride (f16), 400 B

__global__ __launch_bounds__(256, 2) void proj_mfma_kernel(
    const float* __restrict__ x, const _Float16* __restrict__ Wp,
    const float* __restrict__ bias, _Float16* __restrict__ xf)
{
    __shared__ _Float16 hA[64 * PK];   // 25600 B
    const int t = threadIdx.x;
    const int r0 = blockIdx.x * 64;
    const int lane = t & 63;
    const int w = t >> 6;
    const int ln = lane & 15, lq = lane >> 4;

    #pragma unroll
    for (int i = 0; i < 12; ++i) {                 // 3072 float4s
        int idx = t + 256 * i;
        int r = idx / 48, c4 = idx - r * 48;
        float4 v = ((const float4*)(x + (size_t)(r0 + r) * 192))[c4];
        half4v hv; hv[0] = (_Float16)v.x; hv[1] = (_Float16)v.y;
        hv[2] = (_Float16)v.z; hv[3] = (_Float16)v.w;
        *(half4v*)(hA + r * PK + c4 * 4) = hv;
    }
    __syncthreads();

    f32x4 acc[4][3];
    #pragma unroll
    for (int nt = 0; nt < 3; ++nt) {
        float bv = bias[w * 48 + nt * 16 + ln];
        #pragma unroll
        for (int mt = 0; mt < 4; ++mt) acc[mt][nt] = (f32x4){bv, bv, bv, bv};
    }
    #pragma unroll 2
    for (int ks = 0; ks < 6; ++ks) {
        half8 a[4], bf[3];
        #pragma unroll
        for (int mt = 0; mt < 4; ++mt)
            a[mt] = *(const half8*)(hA + (mt * 16 + ln) * PK + ks * 32 + lq * 8);
        #pragma unroll
        for (int nt = 0; nt < 3; ++nt)
            bf[nt] = *(const half8*)(Wp + (size_t)(((w * 3 + nt) * 6 + ks) * 512 + lane * 8));
        #pragma unroll
        for (int nt = 0; nt < 3; ++nt)
            #pragma unroll
            for (int mt = 0; mt < 4; ++mt)
                acc[mt][nt] = __builtin_amdgcn_mfma_f32_16x16x32_f16(a[mt], bf[nt], acc[mt][nt], 0, 0, 0);
    }
    #pragma unroll
    for (int mt = 0; mt < 4; ++mt)
        #pragma unroll
        for (int nt = 0; nt < 3; ++nt)
            #pragma unroll
            for (int r = 0; r < 4; ++r) {
                int m = mt * 16 + lq * 4 + r;
                int n = w * 48 + nt * 16 + ln;
                xf[(size_t)(r0 + m) * 192 + n] = (_Float16)acc[mt][nt][r];
            }
}

// ---------------- fused edge MLP via f16 MFMA, 512 threads / 8 waves ----------------
#define PADK 392   // hA row stride in f16 elements (784 B)

__global__ __launch_bounds__(512, 4) void edge_mlp_kernel(
    const _Float16* __restrict__ xf, const _Float16* __restrict__ qe,
    const int* __restrict__ edges,
    const _Float16* __restrict__ Wp0, const float* __restrict__ b0,
    const _Float16* __restrict__ Wp1, const float* __restrict__ b1,
    const _Float16* __restrict__ Wp2, const float* __restrict__ b2,
    float* __restrict__ seg, float* __restrict__ cnt)
{
    __shared__ _Float16 hA[64 * PADK];   // 50176 B; aliased as f32 h2[64][192] later
    __shared__ int qi[64], gi[64];
    float* h2 = (float*)hA;

    const int t = threadIdx.x;
    const int e0 = blockIdx.x * 64;
    const int lane = t & 63;
    const int w = t >> 6;                // 0..7
    const int ln = lane & 15;            // MFMA n / m low index
    const int lq = lane >> 4;            // quad

    if (t < 64) {
        qi[t] = edges[2 * (e0 + t)];
        gi[t] = edges[2 * (e0 + t) + 1];
    }
    __syncthreads();

    // ---- gather concat(xf[g], qe[q]) into padded LDS, 16B chunks ----
    #pragma unroll
    for (int i = 0; i < 6; ++i) {
        int idx = t + 512 * i;                       // 3072 chunks
        int m = idx / 48, c = idx - m * 48;
        const half8* src = (c < 24) ? ((const half8*)(xf + (size_t)gi[m] * 192) + c)
                                    : ((const half8*)(qe + (size_t)qi[m] * 192) + (c - 24));
        *(half8*)(hA + m * PADK + c * 8) = *src;
    }
    __syncthreads();

    // ---- layers 0,1: 384 -> 384, gelu, in-place. wave w owns 48-col slice ----
    #pragma unroll 1
    for (int L = 0; L < 2; ++L) {
        const _Float16* __restrict__ Wp = L ? Wp1 : Wp0;
        const float* __restrict__ bias = L ? b1 : b0;

        f32x4 acc[4][3];
        #pragma unroll
        for (int nt = 0; nt < 3; ++nt) {
            float bv = bias[w * 48 + nt * 16 + ln];
            #pragma unroll
            for (int mt = 0; mt < 4; ++mt)
                acc[mt][nt] = (f32x4){bv, bv, bv, bv};
        }
        #pragma unroll 2
        for (int ks = 0; ks < 12; ++ks) {
            half8 a[4], bf[3];
            #pragma unroll
            for (int mt = 0; mt < 4; ++mt)
                a[mt] = *(const half8*)(hA + (mt * 16 + ln) * PADK + ks * 32 + lq * 8);
            #pragma unroll
            for (int nt = 0; nt < 3; ++nt)
                bf[nt] = *(const half8*)(Wp + (size_t)(((w * 3 + nt) * 12 + ks) * 512 + lane * 8));
            #pragma unroll
            for (int nt = 0; nt < 3; ++nt)
                #pragma unroll
                for (int mt = 0; mt < 4; ++mt)
                    acc[mt][nt] = __builtin_amdgcn_mfma_f32_16x16x32_f16(a[mt], bf[nt], acc[mt][nt], 0, 0, 0);
        }
        __syncthreads();   // all waves done reading hA
        #pragma unroll
        for (int mt = 0; mt < 4; ++mt)
            #pragma unroll
            for (int nt = 0; nt < 3; ++nt)
                #pragma unroll
                for (int r = 0; r < 4; ++r) {
                    int m = mt * 16 + lq * 4 + r;
                    int n = w * 48 + nt * 16 + ln;
                    hA[m * PADK + n] = (_Float16)gelu_f(acc[mt][nt][r]);
                }
        __syncthreads();
    }

    // ---- layer 2: 384 -> 192. wave w: n-slice (w&3)*48, m-half (w>>2)*32 ----
    {
        const int n0 = (w & 3) * 48;
        const int mh = (w >> 2) * 2;                 // physical m-tile base
        f32x4 acc[2][3];
        #pragma unroll
        for (int nt = 0; nt < 3; ++nt) {
            float bv = b2[n0 + nt * 16 + ln];
            #pragma unroll
            for (int mt = 0; mt < 2; ++mt)
                acc[mt][nt] = (f32x4){bv, bv, bv, bv};
        }
        #pragma unroll 2
        for (int ks = 0; ks < 12; ++ks) {
            half8 a[2], bf[3];
            #pragma unroll
            for (int mt = 0; mt < 2; ++mt)
                a[mt] = *(const half8*)(hA + ((mh + mt) * 16 + ln) * PADK + ks * 32 + lq * 8);
            #pragma unroll
            for (int nt = 0; nt < 3; ++nt)
                bf[nt] = *(const half8*)(Wp2 + (size_t)((((w & 3) * 3 + nt) * 12 + ks) * 512 + lane * 8));
            #pragma unroll
            for (int nt = 0; nt < 3; ++nt)
                #pragma unroll
                for (int mt = 0; mt < 2; ++mt)
                    acc[mt][nt] = __builtin_amdgcn_mfma_f32_16x16x32_f16(a[mt], bf[nt], acc[mt][nt], 0, 0, 0);
        }
        __syncthreads();   // all waves done reading hA; safe to overwrite as h2
        #pragma unroll
        for (int mt = 0; mt < 2; ++mt)
            #pragma unroll
            for (int nt = 0; nt < 3; ++nt)
                #pragma unroll
                for (int r = 0; r < 4; ++r) {
                    int m = (mh + mt) * 16 + lq * 4 + r;
                    int n = n0 + nt * 16 + ln;
                    h2[m * 192 + n] = acc[mt][nt][r];
                }
        __syncthreads();
    }

    // ---- segment reduce within block (qidx sorted), then atomics ----
    if (t < 192) {
        float a = 0.0f;
        for (int m = 0; m < 64; ++m) {
            a += h2[m * 192 + t];
            if (m == 63 || qi[m + 1] != qi[m]) {
                atomicAdd(&seg[(size_t)qi[m] * 192 + t], a);
                a = 0.0f;
            }
        }
    } else if (t == 192) {
        float run = 1.0f;
        for (int m = 1; m < 64; ++m) {
            if (qi[m] != qi[m - 1]) { atomicAdd(&cnt[qi[m - 1]], run); run = 1.0f; }
            else run += 1.0f;
        }
        atomicAdd(&cnt[qi[63]], run);
    }
}

// ---------------- head: m = seg/max(cnt,1); out = gelu(m@W0+b0)@W1+b1 ----------------
#define PSK 196   // ps row stride (f32)

__global__ __launch_bounds__(256, 2) void head_kernel(
    const float* __restrict__ seg, const float* __restrict__ cnt,
    const _Float16* __restrict__ Wp0, const float* __restrict__ b0,
    const float* __restrict__ w1, const float* __restrict__ b1,
    float* __restrict__ out)
{
    __shared__ _Float16 hA[64 * PK];     // 25600 B
    __shared__ float ps[64 * PSK];       // 50176 B
    __shared__ float w1s[192 * 4];
    __shared__ float invc[64];
    const int t = threadIdx.x;
    const int r0 = blockIdx.x * 64;
    const int lane = t & 63;
    const int w = t >> 6;
    const int ln = lane & 15, lq = lane >> 4;

    if (t < 64) invc[t] = 1.0f / fmaxf(cnt[r0 + t], 1.0f);
    if (t < 192) ((float4*)w1s)[t] = ((const float4*)w1)[t];
    __syncthreads();

    #pragma unroll
    for (int i = 0; i < 12; ++i) {
        int idx = t + 256 * i;
        int r = idx / 48, c4 = idx - r * 48;
        float inv = invc[r];
        float4 v = ((const float4*)(seg + (size_t)(r0 + r) * 192))[c4];
        half4v hv; hv[0] = (_Float16)(v.x * inv); hv[1] = (_Float16)(v.y * inv);
        hv[2] = (_Float16)(v.z * inv); hv[3] = (_Float16)(v.w * inv);
        *(half4v*)(hA + r * PK + c4 * 4) = hv;
    }
    __syncthreads();

    f32x4 acc[4][3];
    #pragma unroll
    for (int nt = 0; nt < 3; ++nt) {
        float bv = b0[w * 48 + nt * 16 + ln];
        #pragma unroll
        for (int mt = 0; mt < 4; ++mt) acc[mt][nt] = (f32x4){bv, bv, bv, bv};
    }
    #pragma unroll 2
    for (int ks = 0; ks < 6; ++ks) {
        half8 a[4], bf[3];
        #pragma unroll
        for (int mt = 0; mt < 4; ++mt)
            a[mt] = *(const half8*)(hA + (mt * 16 + ln) * PK + ks * 32 + lq * 8);
        #pragma unroll
        for (int nt = 0; nt < 3; ++nt)
            bf[nt] = *(const half8*)(Wp0 + (size_t)(((w * 3 + nt) * 6 + ks) * 512 + lane * 8));
        #pragma unroll
        for (int nt = 0; nt < 3; ++nt)
            #pragma unroll
            for (int mt = 0; mt < 4; ++mt)
                acc[mt][nt] = __builtin_amdgcn_mfma_f32_16x16x32_f16(a[mt], bf[nt], acc[mt][nt], 0, 0, 0);
    }
    #pragma unroll
    for (int mt = 0; mt < 4; ++mt)
        #pragma unroll
        for (int nt = 0; nt < 3; ++nt)
            #pragma unroll
            for (int r = 0; r < 4; ++r) {
                int m = mt * 16 + lq * 4 + r;
                int n = w * 48 + nt * 16 + ln;
                ps[m * PSK + n] = gelu_f(acc[mt][nt][r]);
            }
    __syncthreads();

    // layer1: 192 -> 4, one thread per (row, out-col)
    {
        int r = t >> 2, oo = t & 3;
        float a = b1[oo];
        for (int k = 0; k < 192; ++k)
            a = fmaf(ps[r * PSK + k], w1s[k * 4 + oo], a);
        out[(size_t)(r0 + r) * 4 + oo] = a;
    }
}

extern "C" void kernel_launch(void* const* d_in, const int* in_sizes, int n_in,
                              void* d_out, int out_size, void* d_ws, size_t ws_size,
                              hipStream_t stream) {
    (void)in_sizes; (void)n_in; (void)out_size; (void)ws_size;
    const float* x       = (const float*)d_in[0];
    const float* qpos    = (const float*)d_in[1];
    const int*   edges   = (const int*)d_in[2];
    const float* proj_w  = (const float*)d_in[3];
    const float* proj_b  = (const float*)d_in[4];
    const float* msg0_w  = (const float*)d_in[5];
    const float* msg0_b  = (const float*)d_in[6];
    const float* msg1_w  = (const float*)d_in[7];
    const float* msg1_b  = (const float*)d_in[8];
    const float* msg2_w  = (const float*)d_in[9];
    const float* msg2_b  = (const float*)d_in[10];
    const float* pred0_w = (const float*)d_in[11];
    const float* pred0_b = (const float*)d_in[12];
    const float* pred1_w = (const float*)d_in[13];
    const float* pred1_b = (const float*)d_in[14];
    float* out = (float*)d_out;

    // ws layout (bytes):
    //  xf  f16: 12582912                    @ 0
    //  qe  f16: 12582912                    @ 12582912
    //  seg f32: 25165824                    @ 25165824
    //  cnt f32: 131072                      @ 50331648
    //  Wp0 f16: 294912                      @ 50462720
    //  Wp1 f16: 294912                      @ 50757632
    //  Wp2 f16: 147456                      @ 51052544
    //  WpP f16: 73728                       @ 51200000
    //  WpH f16: 73728                       @ 51273728
    char* ws = (char*)d_ws;
    _Float16* xf  = (_Float16*)(ws);
    _Float16* qe  = (_Float16*)(ws + 12582912);
    float*    seg = (float*)(ws + 25165824);
    float*    cnt = (float*)(ws + 50331648);
    _Float16* Wp0 = (_Float16*)(ws + 50462720);
    _Float16* Wp1 = (_Float16*)(ws + 50757632);
    _Float16* Wp2 = (_Float16*)(ws + 51052544);
    _Float16* WpP = (_Float16*)(ws + 51200000);
    _Float16* WpH = (_Float16*)(ws + 51273728);

    hipMemsetAsync(seg, 0, 25165824 + 131072, stream);   // seg + cnt
    embed_kernel<<<24576, 256, 0, stream>>>(qpos, qe);
    pack_w_kernel<<<18, 256, 0, stream>>>(proj_w,  WpP, 192, 192);
    pack_w_kernel<<<72, 256, 0, stream>>>(msg0_w, Wp0, 384, 384);
    pack_w_kernel<<<72, 256, 0, stream>>>(msg1_w, Wp1, 384, 384);
    pack_w_kernel<<<36, 256, 0, stream>>>(msg2_w, Wp2, 384, 192);
    pack_w_kernel<<<18, 256, 0, stream>>>(pred0_w, WpH, 192, 192);
    proj_mfma_kernel<<<512, 256, 0, stream>>>(x, WpP, proj_b, xf);
    edge_mlp_kernel<<<4096, 512, 0, stream>>>(xf, qe, edges,
                                              Wp0, msg0_b, Wp1, msg1_b, Wp2, msg2_b,
                                              seg, cnt);
    head_kernel<<<512, 256, 0, stream>>>(seg, cnt, WpH, pred0_b,
                                         pred1_w, pred1_b, out);
}

// Round 5
// 372.380 us; speedup vs baseline: 12.9038x; 1.0906x over previous
//
#include <hip/hip_runtime.h>
#include <math.h>

// Problem constants
#define N_Q    32768
#define N_E    262144
// dims: IN=EMB=192, concat=384, 2*HID=384, BOT=192, PREDH=192, OUT=4

typedef _Float16 half8 __attribute__((ext_vector_type(8)));
typedef _Float16 half4v __attribute__((ext_vector_type(4)));
typedef float f32x4 __attribute__((ext_vector_type(4)));

// A&S 7.1.25 erf (|eps|<=2.5e-5, invisible under f16 storage rounding 5e-4).
// gelu(x) = 0.5x(1+erf(x/sqrt2)) = 0.5(x + |x|*erf(|x|/sqrt2))
// erf(z) = 1 - (a1 t + a2 t^2 + a3 t^3) exp(-z^2), t = 1/(1+0.47047 z)
// folded: z = ax/sqrt2 -> denom = 1 + (0.47047/sqrt2) ax ; exp(-z^2)=exp2(-0.72134752 ax^2)
__device__ __forceinline__ float gelu_f(float x) {
    float ax = fabsf(x);
    float t = __builtin_amdgcn_rcpf(fmaf(0.33269070724668f, ax, 1.0f));
    float poly = t * fmaf(t, fmaf(t, 0.7478556f, -0.0958798f), 0.3480242f);
    float e = exp2f(-0.72134752044448f * ax * ax);
    float u = fmaf(-poly, e, 1.0f);          // erf(z)
    return 0.5f * fmaf(ax, u, x);
}

// ---------------- sincos embedding -> f16 (hw sin/cos on revolutions) ----------------
__global__ __launch_bounds__(256) void embed_kernel(const float* __restrict__ qpos,
                                                    _Float16* __restrict__ qe) {
    int gid = blockIdx.x * 256 + threadIdx.x;   // covers N_Q*96: (q, d, i)
    int q = gid / 96, r = gid - q * 96;
    int d = r >> 5, i = r & 31;
    float omega = exp2f(-(float)i * 0.41524101186092029f);  // log2(10000)/32
    float arg = qpos[q * 3 + d] * omega;
    float rev = arg * 0.15915494309189535f;                  // radians -> revolutions
    rev = rev - floorf(rev);
    float s = __builtin_amdgcn_sinf(rev);
    float c = __builtin_amdgcn_cosf(rev);
    int base = q * 192 + d * 64 + i;
    qe[base] = (_Float16)s;
    qe[base + 32] = (_Float16)c;
}

// ---------------- pack W[K][N] fp32 -> fragment-order f16 (all 5 mats, one launch) ----
// Per (n_tile, ks) a 1KB block; lane l holds B[k=ks*32+(l>>4)*8+j][n=n_tile*16+(l&15)]
__device__ __forceinline__ void pack_one(const float* __restrict__ W,
                                         _Float16* __restrict__ Wp,
                                         int K, int N, int blk0, int tid) {
    int u = blk0 * 256 + tid;                   // one half8 per thread
    if (u * 8 >= K * N) return;
    int l = u & 63, blk = u >> 6;
    int nks = K >> 5;
    int ntile = blk / nks, ks = blk - ntile * nks;
    int n = ntile * 16 + (l & 15);
    int k0 = ks * 32 + (l >> 4) * 8;
    half8 v;
    #pragma unroll
    for (int j = 0; j < 8; ++j) v[j] = (_Float16)W[(size_t)(k0 + j) * N + n];
    *(half8*)(Wp + (size_t)u * 8) = v;
}

__global__ __launch_bounds__(256) void pack_all_kernel(
    const float* __restrict__ pw,  _Float16* __restrict__ WpP,
    const float* __restrict__ m0,  _Float16* __restrict__ Wp0,
    const float* __restrict__ m1,  _Float16* __restrict__ Wp1,
    const float* __restrict__ m2,  _Float16* __restrict__ Wp2,
    const float* __restrict__ hw,  _Float16* __restrict__ WpH) {
    int b = blockIdx.x, t = threadIdx.x;
    if      (b < 18)  pack_one(pw, WpP, 192, 192, b,        t);
    else if (b < 90)  pack_one(m0, Wp0, 384, 384, b - 18,   t);
    else if (b < 162) pack_one(m1, Wp1, 384, 384, b - 90,   t);
    else if (b < 198) pack_one(m2, Wp2, 384, 192, b - 162,  t);
    else              pack_one(hw, WpH, 192, 192, b - 198,  t);
}

// ---------------- proj: xf = f16(x @ proj_w + proj_b), via MFMA ----------------
#define PK 200   // hA row stride (f16), 400 B

__global__ __launch_bounds__(256, 2) void proj_mfma_kernel(
    const float* __restrict__ x, const _Float16* __restrict__ Wp,
    const float* __restrict__ bias, _Float16* __restrict__ xf)
{
    __shared__ _Float16 hA[64 * PK];   // 25600 B
    const int t = threadIdx.x;
    const int r0 = blockIdx.x * 64;
    const int lane = t & 63;
    const int w = t >> 6;
    const int ln = lane & 15, lq = lane >> 4;

    #pragma unroll
    for (int i = 0; i < 12; ++i) {                 // 3072 float4s
        int idx = t + 256 * i;
        int r = idx / 48, c4 = idx - r * 48;
        float4 v = ((const float4*)(x + (size_t)(r0 + r) * 192))[c4];
        half4v hv; hv[0] = (_Float16)v.x; hv[1] = (_Float16)v.y;
        hv[2] = (_Float16)v.z; hv[3] = (_Float16)v.w;
        *(half4v*)(hA + r * PK + c4 * 4) = hv;
    }
    __syncthreads();

    f32x4 acc[4][3];
    #pragma unroll
    for (int nt = 0; nt < 3; ++nt) {
        float bv = bias[w * 48 + nt * 16 + ln];
        #pragma unroll
        for (int mt = 0; mt < 4; ++mt) acc[mt][nt] = (f32x4){bv, bv, bv, bv};
    }
    #pragma unroll 2
    for (int ks = 0; ks < 6; ++ks) {
        half8 a[4], bf[3];
        #pragma unroll
        for (int mt = 0; mt < 4; ++mt)
            a[mt] = *(const half8*)(hA + (mt * 16 + ln) * PK + ks * 32 + lq * 8);
        #pragma unroll
        for (int nt = 0; nt < 3; ++nt)
            bf[nt] = *(const half8*)(Wp + (size_t)(((w * 3 + nt) * 6 + ks) * 512 + lane * 8));
        #pragma unroll
        for (int nt = 0; nt < 3; ++nt)
            #pragma unroll
            for (int mt = 0; mt < 4; ++mt)
                acc[mt][nt] = __builtin_amdgcn_mfma_f32_16x16x32_f16(a[mt], bf[nt], acc[mt][nt], 0, 0, 0);
    }
    #pragma unroll
    for (int mt = 0; mt < 4; ++mt)
        #pragma unroll
        for (int nt = 0; nt < 3; ++nt)
            #pragma unroll
            for (int r = 0; r < 4; ++r) {
                int m = mt * 16 + lq * 4 + r;
                int n = w * 48 + nt * 16 + ln;
                xf[(size_t)(r0 + m) * 192 + n] = (_Float16)acc[mt][nt][r];
            }
}

// ---------------- fused edge MLP via f16 MFMA, 512 threads / 8 waves ----------------
#define PADK 392   // hA row stride in f16 elements (784 B)

__global__ __launch_bounds__(512, 6) void edge_mlp_kernel(
    const _Float16* __restrict__ xf, const _Float16* __restrict__ qe,
    const int* __restrict__ edges,
    const _Float16* __restrict__ Wp0, const float* __restrict__ b0,
    const _Float16* __restrict__ Wp1, const float* __restrict__ b1,
    const _Float16* __restrict__ Wp2, const float* __restrict__ b2,
    float* __restrict__ seg, float* __restrict__ cnt)
{
    __shared__ _Float16 hA[64 * PADK];   // 50176 B; aliased as f32 h2[64][192] later
    __shared__ int qi[64], gi[64];
    float* h2 = (float*)hA;

    const int t = threadIdx.x;
    const int e0 = blockIdx.x * 64;
    const int lane = t & 63;
    const int w = t >> 6;                // 0..7
    const int ln = lane & 15;            // MFMA n / m low index
    const int lq = lane >> 4;            // quad

    if (t < 64) {
        qi[t] = edges[2 * (e0 + t)];
        gi[t] = edges[2 * (e0 + t) + 1];
    }
    __syncthreads();

    // ---- gather concat(xf[g], qe[q]) into padded LDS, 16B chunks ----
    #pragma unroll
    for (int i = 0; i < 6; ++i) {
        int idx = t + 512 * i;                       // 3072 chunks
        int m = idx / 48, c = idx - m * 48;
        const half8* src = (c < 24) ? ((const half8*)(xf + (size_t)gi[m] * 192) + c)
                                    : ((const half8*)(qe + (size_t)qi[m] * 192) + (c - 24));
        *(half8*)(hA + m * PADK + c * 8) = *src;
    }
    __syncthreads();

    // ---- layers 0,1: 384 -> 384, gelu, in-place. wave w owns 48-col slice ----
    #pragma unroll 1
    for (int L = 0; L < 2; ++L) {
        const _Float16* __restrict__ Wp = L ? Wp1 : Wp0;
        const float* __restrict__ bias = L ? b1 : b0;

        f32x4 acc[4][3];
        #pragma unroll
        for (int nt = 0; nt < 3; ++nt) {
            float bv = bias[w * 48 + nt * 16 + ln];
            #pragma unroll
            for (int mt = 0; mt < 4; ++mt)
                acc[mt][nt] = (f32x4){bv, bv, bv, bv};
        }
        #pragma unroll 2
        for (int ks = 0; ks < 12; ++ks) {
            half8 a[4], bf[3];
            #pragma unroll
            for (int mt = 0; mt < 4; ++mt)
                a[mt] = *(const half8*)(hA + (mt * 16 + ln) * PADK + ks * 32 + lq * 8);
            #pragma unroll
            for (int nt = 0; nt < 3; ++nt)
                bf[nt] = *(const half8*)(Wp + (size_t)(((w * 3 + nt) * 12 + ks) * 512 + lane * 8));
            #pragma unroll
            for (int nt = 0; nt < 3; ++nt)
                #pragma unroll
                for (int mt = 0; mt < 4; ++mt)
                    acc[mt][nt] = __builtin_amdgcn_mfma_f32_16x16x32_f16(a[mt], bf[nt], acc[mt][nt], 0, 0, 0);
        }
        __syncthreads();   // all waves done reading hA
        #pragma unroll
        for (int mt = 0; mt < 4; ++mt)
            #pragma unroll
            for (int nt = 0; nt < 3; ++nt)
                #pragma unroll
                for (int r = 0; r < 4; ++r) {
                    int m = mt * 16 + lq * 4 + r;
                    int n = w * 48 + nt * 16 + ln;
                    hA[m * PADK + n] = (_Float16)gelu_f(acc[mt][nt][r]);
                }
        __syncthreads();
    }

    // ---- layer 2: 384 -> 192. wave w: n-slice (w&3)*48, m-half (w>>2)*32 ----
    {
        const int n0 = (w & 3) * 48;
        const int mh = (w >> 2) * 2;                 // physical m-tile base
        f32x4 acc[2][3];
        #pragma unroll
        for (int nt = 0; nt < 3; ++nt) {
            float bv = b2[n0 + nt * 16 + ln];
            #pragma unroll
            for (int mt = 0; mt < 2; ++mt)
                acc[mt][nt] = (f32x4){bv, bv, bv, bv};
        }
        #pragma unroll 2
        for (int ks = 0; ks < 12; ++ks) {
            half8 a[2], bf[3];
            #pragma unroll
            for (int mt = 0; mt < 2; ++mt)
                a[mt] = *(const half8*)(hA + ((mh + mt) * 16 + ln) * PADK + ks * 32 + lq * 8);
            #pragma unroll
            for (int nt = 0; nt < 3; ++nt)
                bf[nt] = *(const half8*)(Wp2 + (size_t)((((w & 3) * 3 + nt) * 12 + ks) * 512 + lane * 8));
            #pragma unroll
            for (int nt = 0; nt < 3; ++nt)
                #pragma unroll
                for (int mt = 0; mt < 2; ++mt)
                    acc[mt][nt] = __builtin_amdgcn_mfma_f32_16x16x32_f16(a[mt], bf[nt], acc[mt][nt], 0, 0, 0);
        }
        __syncthreads();   // all waves done reading hA; safe to overwrite as h2
        #pragma unroll
        for (int mt = 0; mt < 2; ++mt)
            #pragma unroll
            for (int nt = 0; nt < 3; ++nt)
                #pragma unroll
                for (int r = 0; r < 4; ++r) {
                    int m = (mh + mt) * 16 + lq * 4 + r;
                    int n = n0 + nt * 16 + ln;
                    h2[m * 192 + n] = acc[mt][nt][r];
                }
        __syncthreads();
    }

    // ---- segment reduce within block (qidx sorted), 2 row-halves, then atomics ----
    if (t < 384) {
        int half = t >= 192;
        int col = t - half * 192;
        int mlo = half * 32, mhi = mlo + 32;
        float a = 0.0f;
        for (int m = mlo; m < mhi; ++m) {
            a += h2[m * 192 + col];
            if (m == mhi - 1 || qi[m + 1] != qi[m]) {
                atomicAdd(&seg[(size_t)qi[m] * 192 + col], a);
                a = 0.0f;
            }
        }
    } else if (t < 386) {
        int half = t - 384;
        int mlo = half * 32, mhi = mlo + 32;
        float run = 1.0f;
        for (int m = mlo + 1; m < mhi; ++m) {
            if (qi[m] != qi[m - 1]) { atomicAdd(&cnt[qi[m - 1]], run); run = 1.0f; }
            else run += 1.0f;
        }
        atomicAdd(&cnt[qi[mhi - 1]], run);
    }
}

// ---------------- head: m = seg/max(cnt,1); out = gelu(m@W0+b0)@W1+b1 ----------------
#define PSK 196   // ps row stride (f32)

__global__ __launch_bounds__(256, 2) void head_kernel(
    const float* __restrict__ seg, const float* __restrict__ cnt,
    const _Float16* __restrict__ Wp0, const float* __restrict__ b0,
    const float* __restrict__ w1, const float* __restrict__ b1,
    float* __restrict__ out)
{
    __shared__ _Float16 hA[64 * PK];     // 25600 B
    __shared__ float ps[64 * PSK];       // 50176 B
    __shared__ float w1s[192 * 4];
    __shared__ float invc[64];
    const int t = threadIdx.x;
    const int r0 = blockIdx.x * 64;
    const int lane = t & 63;
    const int w = t >> 6;
    const int ln = lane & 15, lq = lane >> 4;

    if (t < 64) invc[t] = 1.0f / fmaxf(cnt[r0 + t], 1.0f);
    if (t < 192) ((float4*)w1s)[t] = ((const float4*)w1)[t];
    __syncthreads();

    #pragma unroll
    for (int i = 0; i < 12; ++i) {
        int idx = t + 256 * i;
        int r = idx / 48, c4 = idx - r * 48;
        float inv = invc[r];
        float4 v = ((const float4*)(seg + (size_t)(r0 + r) * 192))[c4];
        half4v hv; hv[0] = (_Float16)(v.x * inv); hv[1] = (_Float16)(v.y * inv);
        hv[2] = (_Float16)(v.z * inv); hv[3] = (_Float16)(v.w * inv);
        *(half4v*)(hA + r * PK + c4 * 4) = hv;
    }
    __syncthreads();

    f32x4 acc[4][3];
    #pragma unroll
    for (int nt = 0; nt < 3; ++nt) {
        float bv = b0[w * 48 + nt * 16 + ln];
        #pragma unroll
        for (int mt = 0; mt < 4; ++mt) acc[mt][nt] = (f32x4){bv, bv, bv, bv};
    }
    #pragma unroll 2
    for (int ks = 0; ks < 6; ++ks) {
        half8 a[4], bf[3];
        #pragma unroll
        for (int mt = 0; mt < 4; ++mt)
            a[mt] = *(const half8*)(hA + (mt * 16 + ln) * PK + ks * 32 + lq * 8);
        #pragma unroll
        for (int nt = 0; nt < 3; ++nt)
            bf[nt] = *(const half8*)(Wp0 + (size_t)(((w * 3 + nt) * 6 + ks) * 512 + lane * 8));
        #pragma unroll
        for (int nt = 0; nt < 3; ++nt)
            #pragma unroll
            for (int mt = 0; mt < 4; ++mt)
                acc[mt][nt] = __builtin_amdgcn_mfma_f32_16x16x32_f16(a[mt], bf[nt], acc[mt][nt], 0, 0, 0);
    }
    #pragma unroll
    for (int mt = 0; mt < 4; ++mt)
        #pragma unroll
        for (int nt = 0; nt < 3; ++nt)
            #pragma unroll
            for (int r = 0; r < 4; ++r) {
                int m = mt * 16 + lq * 4 + r;
                int n = w * 48 + nt * 16 + ln;
                ps[m * PSK + n] = gelu_f(acc[mt][nt][r]);
            }
    __syncthreads();

    // layer1: 192 -> 4, one thread per (row, out-col)
    {
        int r = t >> 2, oo = t & 3;
        float a = b1[oo];
        for (int k = 0; k < 192; ++k)
            a = fmaf(ps[r * PSK + k], w1s[k * 4 + oo], a);
        out[(size_t)(r0 + r) * 4 + oo] = a;
    }
}

extern "C" void kernel_launch(void* const* d_in, const int* in_sizes, int n_in,
                              void* d_out, int out_size, void* d_ws, size_t ws_size,
                              hipStream_t stream) {
    (void)in_sizes; (void)n_in; (void)out_size; (void)ws_size;
    const float* x       = (const float*)d_in[0];
    const float* qpos    = (const float*)d_in[1];
    const int*   edges   = (const int*)d_in[2];
    const float* proj_w  = (const float*)d_in[3];
    const float* proj_b  = (const float*)d_in[4];
    const float* msg0_w  = (const float*)d_in[5];
    const float* msg0_b  = (const float*)d_in[6];
    const float* msg1_w  = (const float*)d_in[7];
    const float* msg1_b  = (const float*)d_in[8];
    const float* msg2_w  = (const float*)d_in[9];
    const float* msg2_b  = (const float*)d_in[10];
    const float* pred0_w = (const float*)d_in[11];
    const float* pred0_b = (const float*)d_in[12];
    const float* pred1_w = (const float*)d_in[13];
    const float* pred1_b = (const float*)d_in[14];
    float* out = (float*)d_out;

    // ws layout (bytes):
    //  xf  f16: 12582912                    @ 0
    //  qe  f16: 12582912                    @ 12582912
    //  seg f32: 25165824                    @ 25165824
    //  cnt f32: 131072                      @ 50331648
    //  Wp0 f16: 294912                      @ 50462720
    //  Wp1 f16: 294912                      @ 50757632
    //  Wp2 f16: 147456                      @ 51052544
    //  WpP f16: 73728                       @ 51200000
    //  WpH f16: 73728                       @ 51273728
    char* ws = (char*)d_ws;
    _Float16* xf  = (_Float16*)(ws);
    _Float16* qe  = (_Float16*)(ws + 12582912);
    float*    seg = (float*)(ws + 25165824);
    float*    cnt = (float*)(ws + 50331648);
    _Float16* Wp0 = (_Float16*)(ws + 50462720);
    _Float16* Wp1 = (_Float16*)(ws + 50757632);
    _Float16* Wp2 = (_Float16*)(ws + 51052544);
    _Float16* WpP = (_Float16*)(ws + 51200000);
    _Float16* WpH = (_Float16*)(ws + 51273728);

    hipMemsetAsync(seg, 0, 25165824 + 131072, stream);   // seg + cnt
    embed_kernel<<<12288, 256, 0, stream>>>(qpos, qe);   // 32768*96/256
    pack_all_kernel<<<216, 256, 0, stream>>>(proj_w, WpP, msg0_w, Wp0,
                                             msg1_w, Wp1, msg2_w, Wp2,
                                             pred0_w, WpH);
    proj_mfma_kernel<<<512, 256, 0, stream>>>(x, WpP, proj_b, xf);
    edge_mlp_kernel<<<4096, 512, 0, stream>>>(xf, qe, edges,
                                              Wp0, msg0_b, Wp1, msg1_b, Wp2, msg2_b,
                                              seg, cnt);
    head_kernel<<<512, 256, 0, stream>>>(seg, cnt, WpH, pred0_b,
                                         pred1_w, pred1_b, out);
}